// Round 1
// baseline (316.127 us; speedup 1.0000x reference)
//
#include <hip/hip_runtime.h>

// Problem constants (B,C,L fixed by the reference)
#define BB     64
#define CC     12
#define LL     2048
#define KERNSZ 9
#define KK     8     // kernels per group
#define GG     32    // groups per branch (_G)
#define NPER   6
#define NDIL   8
#define PAD    512   // max halo = 4*d, d<=128
#define MAIN   2048
#define BUFSZ  (PAD + MAIN + PAD)   // 3072 floats = 12 KB per wave
#define WPB    4                     // waves per block

__global__ __launch_bounds__(256) void hydra_kernel(
    const float* __restrict__ X,    // [B, C, L]
    const float* __restrict__ W,    // [NDIL, 2, KK*GG, 1, KERNSZ]
    const int*   __restrict__ I,    // [NDIL, 2, GG, NPER]
    float*       __restrict__ out)  // [B, 8192]
{
    __shared__ float lds[WPB][BUFSZ];   // 48 KB/block -> 3 blocks/CU

    const int tid  = threadIdx.x;
    const int wave = tid >> 6;
    const int lane = tid & 63;
    const int wid  = blockIdx.x * WPB + wave;   // 0..32767
    // task decode: wid = b*512 + di*64 + diff*32 + g
    const int b   = wid >> 9;
    const int r   = wid & 511;
    const int di  = r >> 6;
    const int r2  = r & 63;
    const int dif = r2 >> 5;
    const int g   = r2 & 31;
    const int d   = 1 << di;
    const int Lp  = LL - dif;          // 2048 (X) or 2047 (diff X)

    float* buf = lds[wave];
    float* sel = buf + PAD;

    // ---- zero halo pads (branchless dilated taps later) ----
    #pragma unroll
    for (int i = 0; i < PAD; i += 64) {
        buf[i + lane]              = 0.0f;
        buf[PAD + MAIN + i + lane] = 0.0f;
    }

    // ---- phase 1: channel-subset sum S into sel[0..2047] ----
    const int* Ig = I + ((size_t)((di * 2 + dif) * GG + g)) * NPER;
    const float* xb = X + (size_t)b * CC * LL;
    const float* p0 = xb + Ig[0] * LL;
    const float* p1 = xb + Ig[1] * LL;
    const float* p2 = xb + Ig[2] * LL;
    const float* p3 = xb + Ig[3] * LL;
    const float* p4 = xb + Ig[4] * LL;
    const float* p5 = xb + Ig[5] * LL;

    for (int q = 0; q < 32; ++q) {
        int pos = q * 64 + lane;
        float s = p0[pos] + p1[pos] + p2[pos] + p3[pos] + p4[pos] + p5[pos];
        sel[pos] = s;
    }

    if (dif) {
        // in-place wave-synchronous diff: sel[p] = S[p+1]-S[p]; sel[2047]=0.
        // Safe within one wave: each iteration's ds_reads (pos, pos+1) issue
        // before its ds_write; lane63 reads (q+1)*64 which is only written at
        // iteration q+1. sel[2048] is the zeroed right pad.
        for (int q = 0; q < 32; ++q) {
            int pos = q * 64 + lane;
            float a  = sel[pos];
            float an = sel[pos + 1];
            float v  = (pos == (LL - 1)) ? 0.0f : (an - a);
            sel[pos] = v;
        }
    }

    // ---- phase 2: 8 dilated convs + argmax/argmin scatter counts ----
    const float* Wg = W + (size_t)((di * 2 + dif) * (KK * GG) + g * KK) * KERNSZ;
    float w[KK][KERNSZ];
    #pragma unroll
    for (int k = 0; k < KK; ++k)
        #pragma unroll
        for (int j = 0; j < KERNSZ; ++j)
            w[k][j] = Wg[k * KERNSZ + j];

    float accM[KK], accN[KK];
    #pragma unroll
    for (int k = 0; k < KK; ++k) { accM[k] = 0.0f; accN[k] = 0.0f; }

    for (int q = 0; q < 32; ++q) {
        int pos = q * 64 + lane;
        if (pos < Lp) {
            float s[KERNSZ];
            #pragma unroll
            for (int j = 0; j < KERNSZ; ++j)
                s[j] = sel[pos + (j - 4) * d];   // pads make this branchless

            float v[KK];
            #pragma unroll
            for (int k = 0; k < KK; ++k) {
                float acc = w[k][0] * s[0];
                #pragma unroll
                for (int j = 1; j < KERNSZ; ++j)
                    acc = fmaf(w[k][j], s[j], acc);
                v[k] = acc;
            }

            // first-occurrence argmax / argmin (strict compares keep earliest)
            float mv = v[0]; int mi = 0;
            float nv = v[0]; int ni = 0;
            #pragma unroll
            for (int k = 1; k < KK; ++k) {
                bool gt = v[k] > mv;
                mv = gt ? v[k] : mv;  mi = gt ? k : mi;
                bool lt = v[k] < nv;
                nv = lt ? v[k] : nv;  ni = lt ? k : ni;
            }
            #pragma unroll
            for (int k = 0; k < KK; ++k) {
                accM[k] += (mi == k) ? mv : 0.0f;
                accN[k] += (ni == k) ? 1.0f : 0.0f;
            }
        }
    }

    // ---- wave butterfly reduction of the 16 accumulators ----
    #pragma unroll
    for (int k = 0; k < KK; ++k) {
        float a = accM[k];
        float c = accN[k];
        #pragma unroll
        for (int off = 32; off > 0; off >>= 1) {
            a += __shfl_xor(a, off, 64);
            c += __shfl_xor(c, off, 64);
        }
        accM[k] = a;
        accN[k] = c;
    }

    if (lane == 0) {
        // row(which) = ((di*2+dif)*2 + which)*32 + g ; flat = b*8192 + row*8 + k
        float* o = out + (size_t)b * 8192 + (size_t)((di * 2 + dif) * 2) * 256 + g * KK;
        #pragma unroll
        for (int k = 0; k < KK; ++k) {
            o[k]       = accM[k];   // count_max block (which=0)
            o[256 + k] = accN[k];   // count_min block (which=1)
        }
    }
}

extern "C" void kernel_launch(void* const* d_in, const int* in_sizes, int n_in,
                              void* d_out, int out_size, void* d_ws, size_t ws_size,
                              hipStream_t stream) {
    const float* X = (const float*)d_in[0];
    const float* W = (const float*)d_in[1];
    const int*   I = (const int*)d_in[2];
    float* out = (float*)d_out;

    const int total_waves = BB * NDIL * 2 * GG;       // 32768
    const int blocks = total_waves / WPB;             // 8192
    hydra_kernel<<<blocks, 256, 0, stream>>>(X, W, I, out);
}